// Round 14
// baseline (328.689 us; speedup 1.0000x reference)
//
#include <hip/hip_runtime.h>
#include <math.h>

// BagOfConcepts: inp [8,4096,512] f32, codebook [4096,512] f32
constexpr int D  = 512;
constexpr int K  = 4096;
constexpr int BM = 64;
constexpr int BN = 64;
constexpr int BD_LEG = 32;
constexpr int PAD = 4;

#define MARGIN 2.5e-3f     // >= W + 2E (deterministic bound); validated r6-r13
constexpr int RCAP = 12;   // codes per (token,tile) record
constexpr unsigned CAPQ = 8388608u;   // queue capacity (fits ap region: 32 MB)

typedef short short8v __attribute__((ext_vector_type(8)));
typedef float f32x4   __attribute__((ext_vector_type(4)));

// ws layout (fast path)
constexpr size_t SC_OFF   = 0;                          // 4096 f32
constexpr size_t SX_OFF   = 16384;                      // 32768 f32
constexpr size_t KEYS_OFF = SX_OFF + 131072;            // 32768 u64 = 256 KB
constexpr size_t QCNT_OFF = KEYS_OFF + 262144;          // 1 u32 (+pad)
constexpr size_t CBP_OFF  = QCNT_OFF + 4096;            // 4096*512 u16 perm
constexpr size_t WS_NEED  = CBP_OFF + (size_t)K * D * 2;    // ~4.6 MB

__device__ inline unsigned short rne_bf16(float x) {
    unsigned u = __float_as_uint(x);
    return (unsigned short)((u + 0x7FFFu + ((u >> 16) & 1u)) >> 16);
}
__device__ inline unsigned ordkey(float f) {            // monotone f32 -> u32
    unsigned u = __float_as_uint(f);
    return (u & 0x80000000u) ? ~u : (u | 0x80000000u);
}
__device__ inline float fromkey(unsigned k) {
    unsigned u = (k & 0x80000000u) ? (k ^ 0x80000000u) : ~k;
    return __uint_as_float(u);
}
__device__ inline void gload16(const void* g, void* l) {
    __builtin_amdgcn_global_load_lds(
        (const __attribute__((address_space(1))) unsigned*)g,
        (__attribute__((address_space(3))) unsigned*)l, 16, 0, 0);
}

// ---------------- fused prep: {sc + cvt(cb)} | {sx + cvt(inp)}, both 256-row tiles ----
// blocks [0, nb_cb): sc rows 4b..4b+3 (validated body) + cbp slots [256b, 256b+256)
//   slot8 s = [tile(16)][db(16)][j(4)][row(256)]; content cb[tile*256+row][db*32+j*8..+8]
// blocks [nb_cb, ...): sx (BIT-IDENTICAL fmaf chain) + ap in the SAME 256-row layout
// block 0 thread 0 also zeroes qcnt (replaces the memset dispatch; kernel-boundary
// coherence guarantees visibility to compact).
__global__ __launch_bounds__(256)
void prep_kernel(const float* __restrict__ cb, const float* __restrict__ inp,
                 float* __restrict__ sc, unsigned short* __restrict__ cbp,
                 float* __restrict__ sxg, unsigned short* __restrict__ ap,
                 unsigned* __restrict__ qcnt, int nb_cb) {
    const int t = threadIdx.x;
    if (blockIdx.x == 0 && t == 0) *qcnt = 0u;
    if ((int)blockIdx.x < nb_cb) {
        {   // sc part (validated original body)
            const int row  = blockIdx.x * 4 + (t >> 6);
            const int lane = t & 63;
            const float* r = cb + (size_t)row * D + lane * 8;
            float4 v0 = *(const float4*)r;
            float4 v1 = *(const float4*)(r + 4);
            float s = v0.x * v0.x;
            s += v0.y * v0.y; s += v0.z * v0.z; s += v0.w * v0.w;
            s += v1.x * v1.x; s += v1.y * v1.y; s += v1.z * v1.z; s += v1.w * v1.w;
#pragma unroll
            for (int off = 1; off < 64; off <<= 1) s += __shfl_xor(s, off, 64);
            if (lane == 0) sc[row] = s;
        }
        {   // cvt cb -> 256-row-tile layout (validated r13 body)
            const int s   = blockIdx.x * 256 + t;
            const int tile = s >> 14;
            const int db  = (s >> 10) & 15;
            const int j   = (s >> 8) & 3;
            const int row = s & 255;
            const float* sp = cb + (size_t)(tile * 256 + row) * D + db * 32 + j * 8;
            float4 v0 = *(const float4*)sp;
            float4 v1 = *(const float4*)(sp + 4);
            float xs[8] = {v0.x, v0.y, v0.z, v0.w, v1.x, v1.y, v1.z, v1.w};
            union { short8v v; unsigned short u[8]; } H;
#pragma unroll
            for (int i = 0; i < 8; ++i) H.u[i] = rne_bf16(xs[i]);
            *(short8v*)(cbp + (size_t)s * 8) = H.v;
        }
    } else {
        // sx (BIT-IDENTICAL fmaf chain) + ap cvt into 256-row tiles
        const int m0 = ((int)blockIdx.x - nb_cb) * 64;
        const int r  = t >> 2, p = t & 3;
        const int row  = m0 + r;
        const int tile = row >> 8;
        const int rit  = row & 255;
        const float* rowp = inp + (size_t)row * D + p * 128;
        // slot8 = tile*16384 + (p*4 + (g>>2))*1024 + (g&3)*256 + rit
        unsigned short* dbase = ap + ((size_t)tile * 16384 + (size_t)(p * 4) * 1024 + rit) * 8;
        float s = 0.0f;
#pragma unroll
        for (int g = 0; g < 16; ++g) {
            float4 v0 = *(const float4*)(rowp + g * 8);
            float4 v1 = *(const float4*)(rowp + g * 8 + 4);
            s = fmaf(v0.x, v0.x, s); s = fmaf(v0.y, v0.y, s);
            s = fmaf(v0.z, v0.z, s); s = fmaf(v0.w, v0.w, s);
            s = fmaf(v1.x, v1.x, s); s = fmaf(v1.y, v1.y, s);
            s = fmaf(v1.z, v1.z, s); s = fmaf(v1.w, v1.w, s);
            float xs[8] = {v0.x, v0.y, v0.z, v0.w, v1.x, v1.y, v1.z, v1.w};
            union { short8v v; unsigned short u[8]; } H;
#pragma unroll
            for (int i = 0; i < 8; ++i) H.u[i] = rne_bf16(xs[i]);
            *(short8v*)(dbase + ((size_t)(g >> 2) * 1024 + (size_t)(g & 3) * 256) * 8) = H.v;
        }
        s += __shfl_xor(s, 1, 64);
        s += __shfl_xor(s, 2, 64);
        if (p == 0) sxg[row] = s;
    }
}

// ---------------- exact sequential dot (bit-identical to validated path) ----------------
__device__ float exact_dot512(const float* __restrict__ x, const float* __restrict__ c) {
    float s = 0.0f;
#pragma unroll 4
    for (int i = 0; i < 128; ++i) {
        const float4 xv = *(const float4*)(x + i * 4);
        const float4 cv = *(const float4*)(c + i * 4);
        s = fmaf(xv.x, cv.x, s); s = fmaf(xv.y, cv.y, s);
        s = fmaf(xv.z, cv.z, s); s = fmaf(xv.w, cv.w, s);
    }
    return s;
}

// ---------------- stage 1: 256x256 tile GEMM + per-tile argmin records ----------------
// r14: r8/r13 drain-loop structure (validated), geometry 256x256 / 1024 thr (16 waves
// 4x4; wave tile 64x64, acc[4][4] as r13). Staged DMA drops 1.57GB -> 1.05GB/dispatch;
// blocks halve to 2048 -> epilogue amortized 2x. LDS 64KB dbuf -> 2 blocks/CU =
// 32 waves/CU. Staging = 2 gload16/thread/chunk. Epilogue semantics UNCHANGED.
__global__ __launch_bounds__(1024)
void score_kernel(const unsigned short* __restrict__ a_perm,
                  const unsigned short* __restrict__ b_perm,
                  const float* __restrict__ sc,
                  char* __restrict__ records) {
    __shared__ __align__(16) unsigned short lds[2 * 16384];  // 64KB: per buf A@+0, B@+8192 (halves)
    __shared__ unsigned minsh[256];
    __shared__ unsigned cntsh[256];
    __shared__ unsigned short listsh[256][RCAP];             // 6 KB

    const int t    = threadIdx.x;
    const int lane = t & 63;
    const int w    = t >> 6;          // 0..15
    const int wm   = w >> 2;          // 0..3  (64-token row group)
    const int wn   = w & 3;           // 0..3  (64-code col group)
    const int l15  = lane & 15;
    const int lk   = lane >> 4;
    const int bm   = blockIdx.x >> 4; // 0..127 (256-token tiles)
    const int bn   = blockIdx.x & 15; // 0..15  (256-code tiles)

    // per-thread staging pointers (halves); tile = 256 rows * 512 d = 131072 halves,
    // chunk stride = 256*32 = 8192 halves; 1024 slot8/chunk -> 1 load each for A and B
    const unsigned short* gA = a_perm + (size_t)bm * 131072 + (size_t)t * 8;
    const unsigned short* gB = b_perm + (size_t)bn * 131072 + (size_t)t * 8;

    if (t < 256) { minsh[t] = 0xFFFFFFFFu; cntsh[t] = 0u; }

    f32x4 acc[4][4];
#pragma unroll
    for (int i = 0; i < 4; ++i)
#pragma unroll
        for (int j = 0; j < 4; ++j) acc[i][j] = f32x4{0.f, 0.f, 0.f, 0.f};

    // stage one d-chunk: A 1024 slot8 (1 call) + B 1024 slot8 (1 call); wave-uniform dests
    auto STAGE = [&](int soff, int dbuf) {
        gload16(gA + soff, &lds[dbuf + (w * 64) * 8]);
        gload16(gB + soff, &lds[dbuf + 8192 + (w * 64) * 8]);
    };

    STAGE(0, 0);
    __syncthreads();

    // within-chunk layout (halves): (j*256 + row)*8, j = k-subslice = lk
    const unsigned short* lbA = &lds[lk * 2048 + l15 * 8];
    const unsigned short* lbB = &lds[8192 + lk * 2048 + l15 * 8];
    const int mbase = wm * 512;   // wave-uniform (64 rows * 8 halves)
    const int nbase = wn * 512;

    auto COMPUTE = [&](int cur) {
        short8v af[4], bf[4];
#pragma unroll
        for (int mt = 0; mt < 4; ++mt)
            af[mt] = *(const short8v*)(lbA + cur + mbase + mt * 128);
#pragma unroll
        for (int nt = 0; nt < 4; ++nt)
            bf[nt] = *(const short8v*)(lbB + cur + nbase + nt * 128);
#pragma unroll
        for (int mt = 0; mt < 4; ++mt)
#pragma unroll
            for (int nt = 0; nt < 4; ++nt)
                acc[mt][nt] = __builtin_amdgcn_mfma_f32_16x16x32_bf16(af[mt], bf[nt], acc[mt][nt], 0, 0, 0);
    };

    int soff = 8192;   // next chunk to stage
#pragma unroll 1
    for (int p = 0; p < 8; ++p) {
        STAGE(soff, 16384); soff += 8192;
        COMPUTE(0);
        __syncthreads();
        if (p < 7) { STAGE(soff, 0); soff += 8192; }
        COMPUTE(16384);
        __syncthreads();
    }

    // ---- epilogue (validated semantics; 256 tokens, tile = 256 codes) ----
    float scv[4];
#pragma unroll
    for (int nt = 0; nt < 4; ++nt) scv[nt] = sc[bn * 256 + wn * 64 + nt * 16 + l15];

#pragma unroll
    for (int mt = 0; mt < 4; ++mt)
#pragma unroll
        for (int nt = 0; nt < 4; ++nt)
#pragma unroll
            for (int r = 0; r < 4; ++r)
                acc[mt][nt][r] = fmaf(-2.0f, acc[mt][nt][r], scv[nt]);

#pragma unroll
    for (int mt = 0; mt < 4; ++mt)
#pragma unroll
        for (int r = 0; r < 4; ++r) {
            float m4 = fminf(fminf(acc[mt][0][r], acc[mt][1][r]),
                             fminf(acc[mt][2][r], acc[mt][3][r]));
            m4 = fminf(m4, __shfl_xor(m4, 1, 64));
            m4 = fminf(m4, __shfl_xor(m4, 2, 64));
            m4 = fminf(m4, __shfl_xor(m4, 4, 64));
            m4 = fminf(m4, __shfl_xor(m4, 8, 64));
            if (l15 == 0) {
                const int tok = wm * 64 + mt * 16 + lk * 4 + r;
                atomicMin(&minsh[tok], ordkey(m4));
            }
        }
    __syncthreads();

#pragma unroll
    for (int mt = 0; mt < 4; ++mt)
#pragma unroll
        for (int r = 0; r < 4; ++r) {
            const int tok = wm * 64 + mt * 16 + lk * 4 + r;
            const float tmn = fromkey(minsh[tok]) + MARGIN;
#pragma unroll
            for (int nt = 0; nt < 4; ++nt) {
                if (acc[mt][nt][r] <= tmn) {
                    unsigned p = atomicAdd(&cntsh[tok], 1u);
                    if (p < RCAP)
                        listsh[tok][p] = (unsigned short)(bn * 256 + wn * 64 + nt * 16 + l15);
                }
            }
        }
    __syncthreads();

    if (t < 256) {
        const unsigned* lw = (const unsigned*)&listsh[t][0];
        uint4 r0, r1;
        r0.x = __float_as_uint(fromkey(minsh[t]));
        r0.y = cntsh[t];
        r0.z = lw[0]; r0.w = lw[1];
        r1.x = lw[2]; r1.y = lw[3]; r1.z = lw[4]; r1.w = lw[5];
        char* rp = records + ((size_t)(bm * 256 + t) * 16 + bn) * 32;
        *(uint4*)rp = r0;
        *(uint4*)(rp + 16) = r1;
    }
}

// ---------------- stage 2a: compact candidates into a flat queue (UNCHANGED r13) ------
__global__ __launch_bounds__(256)
void compact_kernel(const char* __restrict__ records,
                    unsigned long long* __restrict__ keysg,
                    unsigned* __restrict__ qcnt,
                    unsigned* __restrict__ queue) {
    const int token = blockIdx.x * 256 + threadIdx.x;
    keysg[token] = 0xFFFFFFFFFFFFFFFFull;

    const char* rbase = records + (size_t)token * 16 * 32;
    float mn = __builtin_huge_valf();
#pragma unroll
    for (int i = 0; i < 16; ++i)
        mn = fminf(mn, *(const float*)(rbase + (size_t)i * 32));
    const float thr = mn + MARGIN;

    unsigned my = 0;
#pragma unroll 1
    for (int i = 0; i < 16; ++i) {
        const char* rp = rbase + (size_t)i * 32;
        if (*(const float*)rp <= thr) {
            const unsigned cnt = *(const unsigned*)(rp + 4);
            my += (cnt <= RCAP) ? cnt : 256u;
        }
    }
    unsigned pos = atomicAdd(qcnt, my);
#pragma unroll 1
    for (int i = 0; i < 16; ++i) {
        const char* rp = rbase + (size_t)i * 32;
        if (*(const float*)rp <= thr) {
            const unsigned cnt = *(const unsigned*)(rp + 4);
            if (cnt <= RCAP) {
                const unsigned short* cs = (const unsigned short*)(rp + 8);
                for (unsigned j = 0; j < cnt; ++j) {
                    if (pos < CAPQ) queue[pos] = ((unsigned)token << 12) | cs[j];
                    ++pos;
                }
            } else {
                for (int c2 = 0; c2 < 256; ++c2) {
                    if (pos < CAPQ) queue[pos] = ((unsigned)token << 12) | (unsigned)(i * 256 + c2);
                    ++pos;
                }
            }
        }
    }
}

// ---------- stage 2b: exec — one lane per candidate, exact rescue (+fused safety) -----
__global__ __launch_bounds__(256)
void exec_kernel(const float* __restrict__ inp, const float* __restrict__ cb,
                 const float* __restrict__ sc, const float* __restrict__ sxg,
                 const unsigned* __restrict__ qcnt, const unsigned* __restrict__ queue,
                 unsigned long long* __restrict__ keysg, int nblk64) {
    const unsigned raw = *qcnt;
    unsigned total = raw > CAPQ ? CAPQ : raw;
    const unsigned stride = gridDim.x * 256;
    for (unsigned i = blockIdx.x * 256 + threadIdx.x; i < total; i += stride) {
        const unsigned e = queue[i];
        const int token = e >> 12;
        const int code  = e & 4095;
        const float dot = exact_dot512(inp + (size_t)token * D, cb + (size_t)code * D);
        const float tmp = sxg[token] - 2.0f * dot;   // -2*dot exact => contraction-immune
        const float v   = tmp + sc[code];
        const unsigned long long key =
            ((unsigned long long)__float_as_uint(v) << 32) | (unsigned)code;
        atomicMin(&keysg[token], key);
    }
    // fused safety: full exact scan iff queue overflowed (practically never)
    if (raw > CAPQ && blockIdx.x < (unsigned)nblk64) {
        const int t = threadIdx.x;
        const int m0 = blockIdx.x * 64;
#pragma unroll 1
        for (int tok = 0; tok < 64; ++tok) {
            const int token = m0 + tok;
            const float sxv = sxg[token];
            const float* xrow = inp + (size_t)token * D;
            for (int code = t; code < K; code += 256) {
                const float dot = exact_dot512(xrow, cb + (size_t)code * D);
                const float tmp = sxv - 2.0f * dot;
                const float v   = tmp + sc[code];
                const unsigned long long key =
                    ((unsigned long long)__float_as_uint(v) << 32) | (unsigned)code;
                atomicMin(&keysg[token], key);
            }
        }
    }
}

// ---------------- gather: bit-exact codebook row copy (UNCHANGED) ----------------------
__global__ __launch_bounds__(256)
void gather_kernel(const float* __restrict__ cb,
                   const unsigned long long* __restrict__ keysg,
                   float* __restrict__ out) {
    const int m0 = blockIdx.x * 64;
    __shared__ int bidx[64];
    if (threadIdx.x < 64) bidx[threadIdx.x] = (int)(keysg[m0 + threadIdx.x] & 0xFFFFFFFFull);
    __syncthreads();
    for (int q = threadIdx.x; q < 64 * (D / 4); q += 256) {
        const int r = q >> 7;
        const int c = (q & 127) * 4;
        *(float4*)(out + (size_t)(m0 + r) * D + c) = *(const float4*)(cb + (size_t)bidx[r] * D + c);
    }
}

// ================= LEGACY fallback path (round-1 validated) ==========
__global__ __launch_bounds__(256)
void sc_kernel(const float* __restrict__ cb, float* __restrict__ sc) {
    const int row  = blockIdx.x * 4 + (threadIdx.x >> 6);
    const int lane = threadIdx.x & 63;
    const float* r = cb + (size_t)row * D + lane * 8;
    float4 v0 = *(const float4*)r;
    float4 v1 = *(const float4*)(r + 4);
    float s = v0.x * v0.x;
    s += v0.y * v0.y; s += v0.z * v0.z; s += v0.w * v0.w;
    s += v1.x * v1.x; s += v1.y * v1.y; s += v1.z * v1.z; s += v1.w * v1.w;
#pragma unroll
    for (int off = 1; off < 64; off <<= 1) s += __shfl_xor(s, off, 64);
    if (lane == 0) sc[row] = s;
}

__global__ __launch_bounds__(256)
void vq_kernel(const float* __restrict__ inp, const float* __restrict__ cb,
               const float* __restrict__ sc, float* __restrict__ out) {
    __shared__ __align__(16) float As[BD_LEG][BM + PAD];
    __shared__ __align__(16) float Bs[BD_LEG][BN + PAD];
    __shared__ float sxl[BM];
    __shared__ float scs[BN];
    __shared__ int   bidx[BM];

    const int t  = threadIdx.x;
    const int m0 = blockIdx.x * BM;
    const int tm = t >> 4;
    const int tn = t & 15;
    const float FINF = __builtin_huge_valf();

    {
        const int r = t >> 2, p = t & 3;
        const float* row = inp + (size_t)(m0 + r) * D + p * 128;
        float s = 0.0f;
#pragma unroll
        for (int i = 0; i < 32; ++i) {
            float4 v = *(const float4*)(row + i * 4);
            s = fmaf(v.x, v.x, s); s = fmaf(v.y, v.y, s);
            s = fmaf(v.z, v.z, s); s = fmaf(v.w, v.w, s);
        }
        s += __shfl_xor(s, 1, 64);
        s += __shfl_xor(s, 2, 64);
        if (p == 0) sxl[r] = s;
    }
    __syncthreads();

    float sxm[4];
#pragma unroll
    for (int i = 0; i < 4; ++i) sxm[i] = sxl[tm * 4 + i];

    float runv[4] = {FINF, FINF, FINF, FINF};
    int   runi[4] = {0, 0, 0, 0};
    const int dq = (t & 7) << 2;
    const int mr = t >> 3;

#pragma unroll 1
    for (int kb = 0; kb < K; kb += BN) {
        __syncthreads();
        if (t < BN) scs[t] = sc[kb + t];

        float accl[4][4];
#pragma unroll
        for (int i = 0; i < 4; ++i)
#pragma unroll
            for (int j = 0; j < 4; ++j) accl[i][j] = 0.0f;

#pragma unroll 1
        for (int db = 0; db < D; db += BD_LEG) {
            const float* ap = inp + (size_t)(m0 + mr) * D + db + dq;
            const float* bp = cb  + (size_t)(kb + mr) * D + db + dq;
            float4 av0 = *(const float4*)ap;
            float4 av1 = *(const float4*)(ap + (size_t)32 * D);
            float4 bv0 = *(const float4*)bp;
            float4 bv1 = *(const float4*)(bp + (size_t)32 * D);
            __syncthreads();
            As[dq + 0][mr] = av0.x; As[dq + 1][mr] = av0.y;
            As[dq + 2][mr] = av0.z; As[dq + 3][mr] = av0.w;
            As[dq + 0][mr + 32] = av1.x; As[dq + 1][mr + 32] = av1.y;
            As[dq + 2][mr + 32] = av1.z; As[dq + 3][mr + 32] = av1.w;
            Bs[dq + 0][mr] = bv0.x; Bs[dq + 1][mr] = bv0.y;
            Bs[dq + 2][mr] = bv0.z; Bs[dq + 3][mr] = bv0.w;
            Bs[dq + 0][mr + 32] = bv1.x; Bs[dq + 1][mr + 32] = bv1.y;
            Bs[dq + 2][mr + 32] = bv1.z; Bs[dq + 3][mr + 32] = bv1.w;
            __syncthreads();
#pragma unroll
            for (int d = 0; d < BD_LEG; ++d) {
                const float4 a = *(const float4*)(&As[d][tm * 4]);
                const float4 b = *(const float4*)(&Bs[d][tn * 4]);
                float af[4] = {a.x, a.y, a.z, a.w};
                float bf[4] = {b.x, b.y, b.z, b.w};
#pragma unroll
                for (int i = 0; i < 4; ++i)
#pragma unroll
                    for (int j = 0; j < 4; ++j)
                        accl[i][j] = fmaf(af[i], bf[j], accl[i][j]);
            }
        }
#pragma unroll
        for (int i = 0; i < 4; ++i) {
            float bv = FINF;
            int   bi = 0x7fffffff;
#pragma unroll
            for (int j = 0; j < 4; ++j) {
                const float p = accl[i][j];
                const float tmp = sxm[i] - 2.0f * p;
                const float v   = tmp + scs[tn * 4 + j];
                const int  idx  = kb + tn * 4 + j;
                if (v < bv) { bv = v; bi = idx; }
            }
#pragma unroll
            for (int off = 1; off < 16; off <<= 1) {
                const float ov = __shfl_xor(bv, off, 64);
                const int   oi = __shfl_xor(bi, off, 64);
                if (ov < bv || (ov == bv && oi < bi)) { bv = ov; bi = oi; }
            }
            if (bv < runv[i]) { runv[i] = bv; runi[i] = bi; }
        }
    }
    if (tn == 0) {
#pragma unroll
        for (int i = 0; i < 4; ++i) bidx[tm * 4 + i] = runi[i];
    }
    __syncthreads();
#pragma unroll 1
    for (int q = t; q < BM * (D / 4); q += 256) {
        const int r = q >> 7;
        const int c = (q & 127) * 4;
        const float4 v = *(const float4*)(cb + (size_t)bidx[r] * D + c);
        *(float4*)(out + (size_t)(m0 + r) * D + c) = v;
    }
}

extern "C" void kernel_launch(void* const* d_in, const int* in_sizes, int n_in,
                              void* d_out, int out_size, void* d_ws, size_t ws_size,
                              hipStream_t stream) {
    const float* inp = (const float*)d_in[0];
    const float* cb  = (const float*)d_in[1];
    float* out = (float*)d_out;
    float* sc  = (float*)d_ws;
    const int tokens = in_sizes[0] / D;     // 32768

    const bool fast = (ws_size >= WS_NEED) && (tokens % 256 == 0) &&
                      (in_sizes[1] == K * D) &&
                      ((size_t)out_size * 4 >= (size_t)tokens * D * 2 + (size_t)tokens * 16 * 32);

    if (fast) {
        float* sxg = (float*)((char*)d_ws + SX_OFF);
        unsigned long long* keysg = (unsigned long long*)((char*)d_ws + KEYS_OFF);
        unsigned* qcnt = (unsigned*)((char*)d_ws + QCNT_OFF);
        unsigned short* cbp = (unsigned short*)((char*)d_ws + CBP_OFF);
        unsigned short* ap  = (unsigned short*)d_out;                       // 32 MB scratch
        char* records = (char*)d_out + (size_t)tokens * D * 2;              // 16 MB scratch
        unsigned* queue = (unsigned*)d_out;                                 // overlays ap (dead after score)

        const int nb_cb = K / 4;   // 1024 == (K*D/8)/256 for D=512

        prep_kernel<<<nb_cb + tokens / 64, 256, 0, stream>>>(cb, inp, sc, cbp, sxg, ap, qcnt, nb_cb);
        score_kernel<<<(tokens / 256) * 16, 1024, 0, stream>>>(ap, cbp, sc, records);
        compact_kernel<<<tokens / 256, 256, 0, stream>>>(records, keysg, qcnt, queue);
        exec_kernel<<<2048, 256, 0, stream>>>(inp, cb, sc, sxg, qcnt, queue, keysg, tokens / 64);
        gather_kernel<<<tokens / 64, 256, 0, stream>>>(cb, keysg, out);
    } else {
        sc_kernel<<<K / 4, 256, 0, stream>>>(cb, sc);
        vq_kernel<<<tokens / BM, 256, 0, stream>>>(inp, cb, sc, out);
    }
}

// Round 15
// 286.889 us; speedup vs baseline: 1.1457x; 1.1457x over previous
//
#include <hip/hip_runtime.h>
#include <math.h>

// BagOfConcepts: inp [8,4096,512] f32, codebook [4096,512] f32
constexpr int D  = 512;
constexpr int K  = 4096;
constexpr int BM = 64;
constexpr int BN = 64;
constexpr int BD_LEG = 32;
constexpr int PAD = 4;

#define MARGIN 2.5e-3f     // >= W + 2E; i8 bound 2E+W ~ 1e-3 (rms 7e-5, 5-sigma) << margin
constexpr int RCAP = 12;   // codes per (token,tile) record
constexpr unsigned CAPQ = 4194304u;   // queue capacity: 16 MB region before records

typedef short short8v __attribute__((ext_vector_type(8)));
typedef float f32x4   __attribute__((ext_vector_type(4)));
typedef int   int4v   __attribute__((ext_vector_type(4)));

// ws layout (fast path)
constexpr size_t SC_OFF   = 0;                          // 4096 f32
constexpr size_t SX_OFF   = 16384;                      // 32768 f32
constexpr size_t KEYS_OFF = 147456;                     // 32768 u64
constexpr size_t QCNT_OFF = 409600;                     // 1 u32 (+pad)
constexpr size_t SCS_OFF  = 413696;                     // 4096 f32 code scales
constexpr size_t SXS_OFF  = 430080;                     // 32768 f32 token scales
constexpr size_t CBP_OFF  = 561152;                     // 4096*512 i8 perm (2 MB)
constexpr size_t WS_NEED  = CBP_OFF + (size_t)K * D;    // ~2.66 MB

__device__ inline unsigned ordkey(float f) {            // monotone f32 -> u32
    unsigned u = __float_as_uint(f);
    return (u & 0x80000000u) ? ~u : (u | 0x80000000u);
}
__device__ inline float fromkey(unsigned k) {
    unsigned u = (k & 0x80000000u) ? (k ^ 0x80000000u) : ~k;
    return __uint_as_float(u);
}
__device__ inline void gload16(const void* g, void* l) {
    __builtin_amdgcn_global_load_lds(
        (const __attribute__((address_space(1))) unsigned*)g,
        (__attribute__((address_space(3))) unsigned*)l, 16, 0, 0);
}

// ---------------- fused prep: per-row {sum, absmax, i8 quantize + permute} ------------
// blocks [0, nb_cb): codebook rows (4 thr/row, 64 rows/block) -> sc, scs, cbp
// blocks [nb_cb, ..): input rows -> sxg (BIT-IDENTICAL fmaf chain), sxs, ap
// i8 tile image (16B slots): [tile][db(8)][j(4)][row(rstride)]; slot holds 16 k-bytes
//   cb: rstride=256 (16 tiles); inp: rstride=128 (256 tiles)
__global__ __launch_bounds__(256)
void prep_kernel(const float* __restrict__ cb, const float* __restrict__ inp,
                 float* __restrict__ sc, float* __restrict__ scs,
                 unsigned char* __restrict__ cbp,
                 float* __restrict__ sxg, float* __restrict__ sxs,
                 unsigned char* __restrict__ ap,
                 unsigned* __restrict__ qcnt, int nb_cb) {
    const int t = threadIdx.x;
    if (blockIdx.x == 0 && t == 0) *qcnt = 0u;
    const bool isCB = (int)blockIdx.x < nb_cb;
    const int r = t >> 2, p = t & 3;
    const int row = (isCB ? (int)blockIdx.x : ((int)blockIdx.x - nb_cb)) * 64 + r;
    const float* base = (isCB ? cb : inp) + (size_t)row * D + p * 128;

    // pass 1: sum (validated fmaf chain order) + absmax
    float s = 0.0f, m = 0.0f;
#pragma unroll
    for (int g = 0; g < 16; ++g) {
        float4 v0 = *(const float4*)(base + g * 8);
        float4 v1 = *(const float4*)(base + g * 8 + 4);
        s = fmaf(v0.x, v0.x, s); s = fmaf(v0.y, v0.y, s);
        s = fmaf(v0.z, v0.z, s); s = fmaf(v0.w, v0.w, s);
        s = fmaf(v1.x, v1.x, s); s = fmaf(v1.y, v1.y, s);
        s = fmaf(v1.z, v1.z, s); s = fmaf(v1.w, v1.w, s);
        m = fmaxf(m, fmaxf(fmaxf(fabsf(v0.x), fabsf(v0.y)), fmaxf(fabsf(v0.z), fabsf(v0.w))));
        m = fmaxf(m, fmaxf(fmaxf(fabsf(v1.x), fabsf(v1.y)), fmaxf(fabsf(v1.z), fabsf(v1.w))));
    }
    s += __shfl_xor(s, 1, 64);
    s += __shfl_xor(s, 2, 64);
    m = fmaxf(m, __shfl_xor(m, 1, 64));
    m = fmaxf(m, __shfl_xor(m, 2, 64));
    const float sinv  = (m > 0.0f) ? 127.0f / m : 0.0f;
    const float scale = m * (1.0f / 127.0f);
    if (p == 0) {
        if (isCB) { sc[row] = s;  scs[row] = scale; }
        else      { sxg[row] = s; sxs[row] = scale; }
    }

    // pass 2: quantize + permuted store (8 bytes per g)
    const int rstride = isCB ? 256 : 128;
    const int tile    = isCB ? (row >> 8) : (row >> 7);
    const int rit     = isCB ? (row & 255) : (row & 127);
    unsigned char* dst = isCB ? cbp : ap;
    const size_t tbase = (size_t)tile * (32 * rstride);   // slots per tile = 8*4*rstride
#pragma unroll
    for (int g = 0; g < 16; ++g) {
        float4 v0 = *(const float4*)(base + g * 8);
        float4 v1 = *(const float4*)(base + g * 8 + 4);
        float xs[8] = {v0.x, v0.y, v0.z, v0.w, v1.x, v1.y, v1.z, v1.w};
        unsigned u0 = 0, u1 = 0;
#pragma unroll
        for (int i = 0; i < 4; ++i) {
            int q = (int)rintf(xs[i] * sinv);
            q = q > 127 ? 127 : (q < -127 ? -127 : q);
            u0 |= ((unsigned)(q & 255)) << (8 * i);
        }
#pragma unroll
        for (int i = 4; i < 8; ++i) {
            int q = (int)rintf(xs[i] * sinv);
            q = q > 127 ? 127 : (q < -127 ? -127 : q);
            u1 |= ((unsigned)(q & 255)) << (8 * (i - 4));
        }
        const int db = 2 * p + (g >> 3);
        const int j  = ((16 * p + g) >> 1) & 3;
        const size_t slot = tbase + (size_t)db * (4 * rstride) + (size_t)j * rstride + rit;
        *(unsigned*)(dst + slot * 16 + (g & 1) * 8)     = u0;
        *(unsigned*)(dst + slot * 16 + (g & 1) * 8 + 4) = u1;
    }
}

// ---------------- exact sequential dot (bit-identical to validated path) ----------------
__device__ float exact_dot512(const float* __restrict__ x, const float* __restrict__ c) {
    float s = 0.0f;
#pragma unroll 4
    for (int i = 0; i < 128; ++i) {
        const float4 xv = *(const float4*)(x + i * 4);
        const float4 cv = *(const float4*)(c + i * 4);
        s = fmaf(xv.x, cv.x, s); s = fmaf(xv.y, cv.y, s);
        s = fmaf(xv.z, cv.z, s); s = fmaf(xv.w, cv.w, s);
    }
    return s;
}

// ---------------- stage 1: 128x256 i8 tile GEMM + per-tile argmin records -------------
// r15: r13 drain-loop structure (validated geometry: 512 thr, 8 waves 2x4) with i8
// mfma_i32_16x16x64 (2x rate, K=64/chunk -> 8 chunks, half the barriers, half the DMA).
// v_approx = -2*s_x*s_c*dot_i32 + sc; margin filter semantics UNCHANGED (r6-r14).
__global__ __launch_bounds__(512)
void score_kernel(const unsigned char* __restrict__ a_perm,
                  const unsigned char* __restrict__ b_perm,
                  const float* __restrict__ sc, const float* __restrict__ scs,
                  const float* __restrict__ sxs,
                  char* __restrict__ records) {
    __shared__ __align__(16) unsigned char lds[2 * 24576];  // 48KB: per buf A@+0(8K) B@+8192(16K)
    __shared__ unsigned minsh[128];
    __shared__ unsigned cntsh[128];
    __shared__ unsigned short listsh[128][RCAP];

    const int t    = threadIdx.x;
    const int lane = t & 63;
    const int w    = t >> 6;          // 0..7
    const int wm   = w >> 2;          // 0..1
    const int wn   = w & 3;           // 0..3
    const int l15  = lane & 15;
    const int lk   = lane >> 4;
    const int bm   = blockIdx.x >> 4; // 0..255 (128-token tiles)
    const int bn   = blockIdx.x & 15; // 0..15  (256-code tiles)

    // per-thread staging srcs (bytes): A tile 65536 B, B tile 131072 B
    const unsigned char* gA = a_perm + (size_t)bm * 65536  + (size_t)t * 16;
    const unsigned char* gB = b_perm + (size_t)bn * 131072 + (size_t)t * 16;

    if (t < 128) { minsh[t] = 0xFFFFFFFFu; cntsh[t] = 0u; }

    int4v acc[4][4];
#pragma unroll
    for (int i = 0; i < 4; ++i)
#pragma unroll
        for (int j = 0; j < 4; ++j) acc[i][j] = int4v{0, 0, 0, 0};

    // stage one K=64 chunk: A 512 slots (1 call), B 1024 slots (2 calls)
    auto STAGE = [&](int db, int dbuf) {
        gload16(gA + (size_t)db * 8192,         &lds[dbuf + t * 16]);
        gload16(gB + (size_t)db * 16384,        &lds[dbuf + 8192 + t * 16]);
        gload16(gB + (size_t)db * 16384 + 8192, &lds[dbuf + 16384 + t * 16]);
    };

    STAGE(0, 0);
    __syncthreads();

    // frag bases: A [j(4)][row(128)]x16B, B [j(4)][row(256)]x16B; j = lk
    const unsigned char* lbA = &lds[lk * 2048 + l15 * 16];
    const unsigned char* lbB = &lds[8192 + lk * 4096 + l15 * 16];
    const int mbase = wm * 1024;   // wave-uniform (64 rows * 16 B)
    const int nbase = wn * 1024;

    auto COMPUTE = [&](int cur) {
        int4v af[4], bf[4];
#pragma unroll
        for (int mt = 0; mt < 4; ++mt)
            af[mt] = *(const int4v*)(lbA + cur + mbase + mt * 256);
#pragma unroll
        for (int nt = 0; nt < 4; ++nt)
            bf[nt] = *(const int4v*)(lbB + cur + nbase + nt * 256);
#pragma unroll
        for (int mt = 0; mt < 4; ++mt)
#pragma unroll
            for (int nt = 0; nt < 4; ++nt)
                acc[mt][nt] = __builtin_amdgcn_mfma_i32_16x16x64_i8(af[mt], bf[nt], acc[mt][nt], 0, 0, 0);
    };

    int sdb = 1;
#pragma unroll 1
    for (int p = 0; p < 4; ++p) {
        STAGE(sdb, 24576); ++sdb;
        COMPUTE(0);
        __syncthreads();
        if (p < 3) { STAGE(sdb, 0); ++sdb; }
        COMPUTE(24576);
        __syncthreads();
    }

    // ---- epilogue (validated semantics; v = -2*s_x*s_c*dot + sc, in-place bitcast) ----
    float scvv[4], scsv[4];
#pragma unroll
    for (int nt = 0; nt < 4; ++nt) {
        const int code = bn * 256 + wn * 64 + nt * 16 + l15;
        scvv[nt] = sc[code];
        scsv[nt] = scs[code];
    }
    float sxsv[4][4];
#pragma unroll
    for (int mt = 0; mt < 4; ++mt)
#pragma unroll
        for (int rr = 0; rr < 4; ++rr)
            sxsv[mt][rr] = sxs[bm * 128 + wm * 64 + mt * 16 + lk * 4 + rr];

#pragma unroll
    for (int mt = 0; mt < 4; ++mt)
#pragma unroll
        for (int nt = 0; nt < 4; ++nt)
#pragma unroll
            for (int rr = 0; rr < 4; ++rr) {
                const float df = (float)acc[mt][nt][rr];   // exact: |dot| < 2^24
                const float vv = fmaf(-2.0f * sxsv[mt][rr] * scsv[nt], df, scvv[nt]);
                acc[mt][nt][rr] = __float_as_int(vv);
            }
#define VACC(mt, nt, rr) __int_as_float(acc[mt][nt][rr])

#pragma unroll
    for (int mt = 0; mt < 4; ++mt)
#pragma unroll
        for (int rr = 0; rr < 4; ++rr) {
            float m4 = fminf(fminf(VACC(mt, 0, rr), VACC(mt, 1, rr)),
                             fminf(VACC(mt, 2, rr), VACC(mt, 3, rr)));
            m4 = fminf(m4, __shfl_xor(m4, 1, 64));
            m4 = fminf(m4, __shfl_xor(m4, 2, 64));
            m4 = fminf(m4, __shfl_xor(m4, 4, 64));
            m4 = fminf(m4, __shfl_xor(m4, 8, 64));
            if (l15 == 0) {
                const int tok = wm * 64 + mt * 16 + lk * 4 + rr;
                atomicMin(&minsh[tok], ordkey(m4));
            }
        }
    __syncthreads();

#pragma unroll
    for (int mt = 0; mt < 4; ++mt)
#pragma unroll
        for (int rr = 0; rr < 4; ++rr) {
            const int tok = wm * 64 + mt * 16 + lk * 4 + rr;
            const float tmn = fromkey(minsh[tok]) + MARGIN;
#pragma unroll
            for (int nt = 0; nt < 4; ++nt) {
                if (VACC(mt, nt, rr) <= tmn) {
                    unsigned p = atomicAdd(&cntsh[tok], 1u);
                    if (p < RCAP)
                        listsh[tok][p] = (unsigned short)(bn * 256 + wn * 64 + nt * 16 + l15);
                }
            }
        }
    __syncthreads();
#undef VACC

    if (t < 128) {
        const unsigned* lw = (const unsigned*)&listsh[t][0];
        uint4 r0, r1;
        r0.x = __float_as_uint(fromkey(minsh[t]));
        r0.y = cntsh[t];
        r0.z = lw[0]; r0.w = lw[1];
        r1.x = lw[2]; r1.y = lw[3]; r1.z = lw[4]; r1.w = lw[5];
        char* rp = records + ((size_t)(bm * 128 + t) * 16 + bn) * 32;
        *(uint4*)rp = r0;
        *(uint4*)(rp + 16) = r1;
    }
}

// ---------------- stage 2a: compact candidates into a flat queue (validated r13/r14) --
__global__ __launch_bounds__(256)
void compact_kernel(const char* __restrict__ records,
                    unsigned long long* __restrict__ keysg,
                    unsigned* __restrict__ qcnt,
                    unsigned* __restrict__ queue) {
    const int token = blockIdx.x * 256 + threadIdx.x;
    keysg[token] = 0xFFFFFFFFFFFFFFFFull;

    const char* rbase = records + (size_t)token * 16 * 32;
    float mn = __builtin_huge_valf();
#pragma unroll
    for (int i = 0; i < 16; ++i)
        mn = fminf(mn, *(const float*)(rbase + (size_t)i * 32));
    const float thr = mn + MARGIN;

    unsigned my = 0;
#pragma unroll 1
    for (int i = 0; i < 16; ++i) {
        const char* rp = rbase + (size_t)i * 32;
        if (*(const float*)rp <= thr) {
            const unsigned cnt = *(const unsigned*)(rp + 4);
            my += (cnt <= RCAP) ? cnt : 256u;
        }
    }
    unsigned pos = atomicAdd(qcnt, my);
#pragma unroll 1
    for (int i = 0; i < 16; ++i) {
        const char* rp = rbase + (size_t)i * 32;
        if (*(const float*)rp <= thr) {
            const unsigned cnt = *(const unsigned*)(rp + 4);
            if (cnt <= RCAP) {
                const unsigned short* cs = (const unsigned short*)(rp + 8);
                for (unsigned j = 0; j < cnt; ++j) {
                    if (pos < CAPQ) queue[pos] = ((unsigned)token << 12) | cs[j];
                    ++pos;
                }
            } else {
                for (int c2 = 0; c2 < 256; ++c2) {
                    if (pos < CAPQ) queue[pos] = ((unsigned)token << 12) | (unsigned)(i * 256 + c2);
                    ++pos;
                }
            }
        }
    }
}

// ---------- stage 2b: exec — one lane per candidate, exact rescue (+fused safety) -----
__global__ __launch_bounds__(256)
void exec_kernel(const float* __restrict__ inp, const float* __restrict__ cb,
                 const float* __restrict__ sc, const float* __restrict__ sxg,
                 const unsigned* __restrict__ qcnt, const unsigned* __restrict__ queue,
                 unsigned long long* __restrict__ keysg, int nblk64) {
    const unsigned raw = *qcnt;
    unsigned total = raw > CAPQ ? CAPQ : raw;
    const unsigned stride = gridDim.x * 256;
    for (unsigned i = blockIdx.x * 256 + threadIdx.x; i < total; i += stride) {
        const unsigned e = queue[i];
        const int token = e >> 12;
        const int code  = e & 4095;
        const float dot = exact_dot512(inp + (size_t)token * D, cb + (size_t)code * D);
        const float tmp = sxg[token] - 2.0f * dot;   // -2*dot exact => contraction-immune
        const float v   = tmp + sc[code];
        const unsigned long long key =
            ((unsigned long long)__float_as_uint(v) << 32) | (unsigned)code;
        atomicMin(&keysg[token], key);
    }
    // fused safety: full exact scan iff queue overflowed (practically never)
    if (raw > CAPQ && blockIdx.x < (unsigned)nblk64) {
        const int t = threadIdx.x;
        const int m0 = blockIdx.x * 64;
#pragma unroll 1
        for (int tok = 0; tok < 64; ++tok) {
            const int token = m0 + tok;
            const float sxv = sxg[token];
            const float* xrow = inp + (size_t)token * D;
            for (int code = t; code < K; code += 256) {
                const float dot = exact_dot512(xrow, cb + (size_t)code * D);
                const float tmp = sxv - 2.0f * dot;
                const float v   = tmp + sc[code];
                const unsigned long long key =
                    ((unsigned long long)__float_as_uint(v) << 32) | (unsigned)code;
                atomicMin(&keysg[token], key);
            }
        }
    }
}

// ---------------- gather: bit-exact codebook row copy (UNCHANGED) ----------------------
__global__ __launch_bounds__(256)
void gather_kernel(const float* __restrict__ cb,
                   const unsigned long long* __restrict__ keysg,
                   float* __restrict__ out) {
    const int m0 = blockIdx.x * 64;
    __shared__ int bidx[64];
    if (threadIdx.x < 64) bidx[threadIdx.x] = (int)(keysg[m0 + threadIdx.x] & 0xFFFFFFFFull);
    __syncthreads();
    for (int q = threadIdx.x; q < 64 * (D / 4); q += 256) {
        const int r = q >> 7;
        const int c = (q & 127) * 4;
        *(float4*)(out + (size_t)(m0 + r) * D + c) = *(const float4*)(cb + (size_t)bidx[r] * D + c);
    }
}

// ================= LEGACY fallback path (round-1 validated) ==========
__global__ __launch_bounds__(256)
void sc_kernel(const float* __restrict__ cb, float* __restrict__ sc) {
    const int row  = blockIdx.x * 4 + (threadIdx.x >> 6);
    const int lane = threadIdx.x & 63;
    const float* r = cb + (size_t)row * D + lane * 8;
    float4 v0 = *(const float4*)r;
    float4 v1 = *(const float4*)(r + 4);
    float s = v0.x * v0.x;
    s += v0.y * v0.y; s += v0.z * v0.z; s += v0.w * v0.w;
    s += v1.x * v1.x; s += v1.y * v1.y; s += v1.z * v1.z; s += v1.w * v1.w;
#pragma unroll
    for (int off = 1; off < 64; off <<= 1) s += __shfl_xor(s, off, 64);
    if (lane == 0) sc[row] = s;
}

__global__ __launch_bounds__(256)
void vq_kernel(const float* __restrict__ inp, const float* __restrict__ cb,
               const float* __restrict__ sc, float* __restrict__ out) {
    __shared__ __align__(16) float As[BD_LEG][BM + PAD];
    __shared__ __align__(16) float Bs[BD_LEG][BN + PAD];
    __shared__ float sxl[BM];
    __shared__ float scs_l[BN];
    __shared__ int   bidx[BM];

    const int t  = threadIdx.x;
    const int m0 = blockIdx.x * BM;
    const int tm = t >> 4;
    const int tn = t & 15;
    const float FINF = __builtin_huge_valf();

    {
        const int r = t >> 2, p = t & 3;
        const float* row = inp + (size_t)(m0 + r) * D + p * 128;
        float s = 0.0f;
#pragma unroll
        for (int i = 0; i < 32; ++i) {
            float4 v = *(const float4*)(row + i * 4);
            s = fmaf(v.x, v.x, s); s = fmaf(v.y, v.y, s);
            s = fmaf(v.z, v.z, s); s = fmaf(v.w, v.w, s);
        }
        s += __shfl_xor(s, 1, 64);
        s += __shfl_xor(s, 2, 64);
        if (p == 0) sxl[r] = s;
    }
    __syncthreads();

    float sxm[4];
#pragma unroll
    for (int i = 0; i < 4; ++i) sxm[i] = sxl[tm * 4 + i];

    float runv[4] = {FINF, FINF, FINF, FINF};
    int   runi[4] = {0, 0, 0, 0};
    const int dq = (t & 7) << 2;
    const int mr = t >> 3;

#pragma unroll 1
    for (int kb = 0; kb < K; kb += BN) {
        __syncthreads();
        if (t < BN) scs_l[t] = sc[kb + t];

        float accl[4][4];
#pragma unroll
        for (int i = 0; i < 4; ++i)
#pragma unroll
            for (int j = 0; j < 4; ++j) accl[i][j] = 0.0f;

#pragma unroll 1
        for (int db = 0; db < D; db += BD_LEG) {
            const float* ap = inp + (size_t)(m0 + mr) * D + db + dq;
            const float* bp = cb  + (size_t)(kb + mr) * D + db + dq;
            float4 av0 = *(const float4*)ap;
            float4 av1 = *(const float4*)(ap + (size_t)32 * D);
            float4 bv0 = *(const float4*)bp;
            float4 bv1 = *(const float4*)(bp + (size_t)32 * D);
            __syncthreads();
            As[dq + 0][mr] = av0.x; As[dq + 1][mr] = av0.y;
            As[dq + 2][mr] = av0.z; As[dq + 3][mr] = av0.w;
            As[dq + 0][mr + 32] = av1.x; As[dq + 1][mr + 32] = av1.y;
            As[dq + 2][mr + 32] = av1.z; As[dq + 3][mr + 32] = av1.w;
            Bs[dq + 0][mr] = bv0.x; Bs[dq + 1][mr] = bv0.y;
            Bs[dq + 2][mr] = bv0.z; Bs[dq + 3][mr] = bv0.w;
            Bs[dq + 0][mr + 32] = bv1.x; Bs[dq + 1][mr + 32] = bv1.y;
            Bs[dq + 2][mr + 32] = bv1.z; Bs[dq + 3][mr + 32] = bv1.w;
            __syncthreads();
#pragma unroll
            for (int d = 0; d < BD_LEG; ++d) {
                const float4 a = *(const float4*)(&As[d][tm * 4]);
                const float4 b = *(const float4*)(&Bs[d][tn * 4]);
                float af[4] = {a.x, a.y, a.z, a.w};
                float bf[4] = {b.x, b.y, b.z, b.w};
#pragma unroll
                for (int i = 0; i < 4; ++i)
#pragma unroll
                    for (int j = 0; j < 4; ++j)
                        accl[i][j] = fmaf(af[i], bf[j], accl[i][j]);
            }
        }
#pragma unroll
        for (int i = 0; i < 4; ++i) {
            float bv = FINF;
            int   bi = 0x7fffffff;
#pragma unroll
            for (int j = 0; j < 4; ++j) {
                const float p = accl[i][j];
                const float tmp = sxm[i] - 2.0f * p;
                const float v   = tmp + scs_l[tn * 4 + j];
                const int  idx  = kb + tn * 4 + j;
                if (v < bv) { bv = v; bi = idx; }
            }
#pragma unroll
            for (int off = 1; off < 16; off <<= 1) {
                const float ov = __shfl_xor(bv, off, 64);
                const int   oi = __shfl_xor(bi, off, 64);
                if (ov < bv || (ov == bv && oi < bi)) { bv = ov; bi = oi; }
            }
            if (bv < runv[i]) { runv[i] = bv; runi[i] = bi; }
        }
    }
    if (tn == 0) {
#pragma unroll
        for (int i = 0; i < 4; ++i) bidx[tm * 4 + i] = runi[i];
    }
    __syncthreads();
#pragma unroll 1
    for (int q = t; q < BM * (D / 4); q += 256) {
        const int r = q >> 7;
        const int c = (q & 127) * 4;
        const float4 v = *(const float4*)(cb + (size_t)bidx[r] * D + c);
        *(float4*)(out + (size_t)(m0 + r) * D + c) = v;
    }
}

extern "C" void kernel_launch(void* const* d_in, const int* in_sizes, int n_in,
                              void* d_out, int out_size, void* d_ws, size_t ws_size,
                              hipStream_t stream) {
    const float* inp = (const float*)d_in[0];
    const float* cb  = (const float*)d_in[1];
    float* out = (float*)d_out;
    float* sc  = (float*)d_ws;
    const int tokens = in_sizes[0] / D;     // 32768

    const bool fast = (ws_size >= WS_NEED) && (tokens % 256 == 0) &&
                      (in_sizes[1] == K * D) &&
                      ((size_t)out_size * 4 >= (size_t)tokens * D + (size_t)tokens * 16 * 32);

    if (fast) {
        float* sxg = (float*)((char*)d_ws + SX_OFF);
        unsigned long long* keysg = (unsigned long long*)((char*)d_ws + KEYS_OFF);
        unsigned* qcnt = (unsigned*)((char*)d_ws + QCNT_OFF);
        float* scsg = (float*)((char*)d_ws + SCS_OFF);
        float* sxsg = (float*)((char*)d_ws + SXS_OFF);
        unsigned char* cbp = (unsigned char*)((char*)d_ws + CBP_OFF);
        unsigned char* ap  = (unsigned char*)d_out;                         // 16 MB i8 scratch
        char* records = (char*)d_out + (size_t)tokens * D;                  // 16 MB scratch
        unsigned* queue = (unsigned*)d_out;                                 // overlays ap (dead after score)

        const int nb_cb = K / 64;   // 64 blocks of 64 rows

        prep_kernel<<<nb_cb + tokens / 64, 256, 0, stream>>>(cb, inp, sc, scsg, cbp,
                                                             sxg, sxsg, ap, qcnt, nb_cb);
        score_kernel<<<(tokens / 128) * 16, 512, 0, stream>>>(ap, cbp, sc, scsg, sxsg, records);
        compact_kernel<<<tokens / 256, 256, 0, stream>>>(records, keysg, qcnt, queue);
        exec_kernel<<<2048, 256, 0, stream>>>(inp, cb, sc, sxg, qcnt, queue, keysg, tokens / 64);
        gather_kernel<<<tokens / 64, 256, 0, stream>>>(cb, keysg, out);
    } else {
        sc_kernel<<<K / 4, 256, 0, stream>>>(cb, sc);
        vq_kernel<<<tokens / BM, 256, 0, stream>>>(inp, cb, sc, out);
    }
}

// Round 16
// 261.948 us; speedup vs baseline: 1.2548x; 1.0952x over previous
//
#include <hip/hip_runtime.h>
#include <math.h>

// BagOfConcepts: inp [8,4096,512] f32, codebook [4096,512] f32
constexpr int D  = 512;
constexpr int K  = 4096;
constexpr int BM = 64;
constexpr int BN = 64;
constexpr int BD_LEG = 32;
constexpr int PAD = 4;

#define MARGIN 2.5e-3f     // >= W + 2E; i8 bound ~1e-3 << margin (validated r15)
constexpr int RCAP = 12;   // codes per (token,tile) record
constexpr int LCAP = 3072; // per-block (64-token) LDS candidate queue

typedef short short8v __attribute__((ext_vector_type(8)));
typedef float f32x4   __attribute__((ext_vector_type(4)));
typedef int   int4v   __attribute__((ext_vector_type(4)));

// ws layout (fast path)
constexpr size_t SC_OFF   = 0;                          // 4096 f32
constexpr size_t SX_OFF   = 16384;                      // 32768 f32
constexpr size_t SCS_OFF  = 147456;                     // 4096 f32 code scales
constexpr size_t SXS_OFF  = 163840;                     // 32768 f32 token scales
constexpr size_t CBP_OFF  = 294912;                     // 4096*512 i8 perm (2 MB)
constexpr size_t WS_NEED  = CBP_OFF + (size_t)K * D;    // ~2.4 MB

__device__ inline unsigned ordkey(float f) {            // monotone f32 -> u32
    unsigned u = __float_as_uint(f);
    return (u & 0x80000000u) ? ~u : (u | 0x80000000u);
}
__device__ inline float fromkey(unsigned k) {
    unsigned u = (k & 0x80000000u) ? (k ^ 0x80000000u) : ~k;
    return __uint_as_float(u);
}
__device__ inline void gload16(const void* g, void* l) {
    __builtin_amdgcn_global_load_lds(
        (const __attribute__((address_space(1))) unsigned*)g,
        (__attribute__((address_space(3))) unsigned*)l, 16, 0, 0);
}

// ---------------- fused prep: per-row {sum, absmax, i8 quantize + permute} ------------
// (validated r15 body; qcnt removed)
__global__ __launch_bounds__(256)
void prep_kernel(const float* __restrict__ cb, const float* __restrict__ inp,
                 float* __restrict__ sc, float* __restrict__ scs,
                 unsigned char* __restrict__ cbp,
                 float* __restrict__ sxg, float* __restrict__ sxs,
                 unsigned char* __restrict__ ap, int nb_cb) {
    const int t = threadIdx.x;
    const bool isCB = (int)blockIdx.x < nb_cb;
    const int r = t >> 2, p = t & 3;
    const int row = (isCB ? (int)blockIdx.x : ((int)blockIdx.x - nb_cb)) * 64 + r;
    const float* base = (isCB ? cb : inp) + (size_t)row * D + p * 128;

    // pass 1: sum (validated fmaf chain order) + absmax
    float s = 0.0f, m = 0.0f;
#pragma unroll
    for (int g = 0; g < 16; ++g) {
        float4 v0 = *(const float4*)(base + g * 8);
        float4 v1 = *(const float4*)(base + g * 8 + 4);
        s = fmaf(v0.x, v0.x, s); s = fmaf(v0.y, v0.y, s);
        s = fmaf(v0.z, v0.z, s); s = fmaf(v0.w, v0.w, s);
        s = fmaf(v1.x, v1.x, s); s = fmaf(v1.y, v1.y, s);
        s = fmaf(v1.z, v1.z, s); s = fmaf(v1.w, v1.w, s);
        m = fmaxf(m, fmaxf(fmaxf(fabsf(v0.x), fabsf(v0.y)), fmaxf(fabsf(v0.z), fabsf(v0.w))));
        m = fmaxf(m, fmaxf(fmaxf(fabsf(v1.x), fabsf(v1.y)), fmaxf(fabsf(v1.z), fabsf(v1.w))));
    }
    s += __shfl_xor(s, 1, 64);
    s += __shfl_xor(s, 2, 64);
    m = fmaxf(m, __shfl_xor(m, 1, 64));
    m = fmaxf(m, __shfl_xor(m, 2, 64));
    const float sinv  = (m > 0.0f) ? 127.0f / m : 0.0f;
    const float scale = m * (1.0f / 127.0f);
    if (p == 0) {
        if (isCB) { sc[row] = s;  scs[row] = scale; }
        else      { sxg[row] = s; sxs[row] = scale; }
    }

    // pass 2: quantize + permuted store (8 bytes per g)
    const int rstride = isCB ? 256 : 128;
    const int tile    = isCB ? (row >> 8) : (row >> 7);
    const int rit     = isCB ? (row & 255) : (row & 127);
    unsigned char* dst = isCB ? cbp : ap;
    const size_t tbase = (size_t)tile * (32 * rstride);
#pragma unroll
    for (int g = 0; g < 16; ++g) {
        float4 v0 = *(const float4*)(base + g * 8);
        float4 v1 = *(const float4*)(base + g * 8 + 4);
        float xs[8] = {v0.x, v0.y, v0.z, v0.w, v1.x, v1.y, v1.z, v1.w};
        unsigned u0 = 0, u1 = 0;
#pragma unroll
        for (int i = 0; i < 4; ++i) {
            int q = (int)rintf(xs[i] * sinv);
            q = q > 127 ? 127 : (q < -127 ? -127 : q);
            u0 |= ((unsigned)(q & 255)) << (8 * i);
        }
#pragma unroll
        for (int i = 4; i < 8; ++i) {
            int q = (int)rintf(xs[i] * sinv);
            q = q > 127 ? 127 : (q < -127 ? -127 : q);
            u1 |= ((unsigned)(q & 255)) << (8 * (i - 4));
        }
        const int db = 2 * p + (g >> 3);
        const int j  = ((16 * p + g) >> 1) & 3;
        const size_t slot = tbase + (size_t)db * (4 * rstride) + (size_t)j * rstride + rit;
        *(unsigned*)(dst + slot * 16 + (g & 1) * 8)     = u0;
        *(unsigned*)(dst + slot * 16 + (g & 1) * 8 + 4) = u1;
    }
}

// ---------------- exact sequential dot (bit-identical to validated path) ----------------
__device__ float exact_dot512(const float* __restrict__ x, const float* __restrict__ c) {
    float s = 0.0f;
#pragma unroll 4
    for (int i = 0; i < 128; ++i) {
        const float4 xv = *(const float4*)(x + i * 4);
        const float4 cv = *(const float4*)(c + i * 4);
        s = fmaf(xv.x, cv.x, s); s = fmaf(xv.y, cv.y, s);
        s = fmaf(xv.z, cv.z, s); s = fmaf(xv.w, cv.w, s);
    }
    return s;
}

// ---------------- stage 1: 128x256 i8 tile GEMM + per-tile argmin records -------------
// (UNCHANGED from validated r15: 139us, absmax 0)
__global__ __launch_bounds__(512)
void score_kernel(const unsigned char* __restrict__ a_perm,
                  const unsigned char* __restrict__ b_perm,
                  const float* __restrict__ sc, const float* __restrict__ scs,
                  const float* __restrict__ sxs,
                  char* __restrict__ records) {
    __shared__ __align__(16) unsigned char lds[2 * 24576];  // 48KB
    __shared__ unsigned minsh[128];
    __shared__ unsigned cntsh[128];
    __shared__ unsigned short listsh[128][RCAP];

    const int t    = threadIdx.x;
    const int lane = t & 63;
    const int w    = t >> 6;
    const int wm   = w >> 2;
    const int wn   = w & 3;
    const int l15  = lane & 15;
    const int lk   = lane >> 4;
    const int bm   = blockIdx.x >> 4;
    const int bn   = blockIdx.x & 15;

    const unsigned char* gA = a_perm + (size_t)bm * 65536  + (size_t)t * 16;
    const unsigned char* gB = b_perm + (size_t)bn * 131072 + (size_t)t * 16;

    if (t < 128) { minsh[t] = 0xFFFFFFFFu; cntsh[t] = 0u; }

    int4v acc[4][4];
#pragma unroll
    for (int i = 0; i < 4; ++i)
#pragma unroll
        for (int j = 0; j < 4; ++j) acc[i][j] = int4v{0, 0, 0, 0};

    auto STAGE = [&](int db, int dbuf) {
        gload16(gA + (size_t)db * 8192,         &lds[dbuf + t * 16]);
        gload16(gB + (size_t)db * 16384,        &lds[dbuf + 8192 + t * 16]);
        gload16(gB + (size_t)db * 16384 + 8192, &lds[dbuf + 16384 + t * 16]);
    };

    STAGE(0, 0);
    __syncthreads();

    const unsigned char* lbA = &lds[lk * 2048 + l15 * 16];
    const unsigned char* lbB = &lds[8192 + lk * 4096 + l15 * 16];
    const int mbase = wm * 1024;
    const int nbase = wn * 1024;

    auto COMPUTE = [&](int cur) {
        int4v af[4], bf[4];
#pragma unroll
        for (int mt = 0; mt < 4; ++mt)
            af[mt] = *(const int4v*)(lbA + cur + mbase + mt * 256);
#pragma unroll
        for (int nt = 0; nt < 4; ++nt)
            bf[nt] = *(const int4v*)(lbB + cur + nbase + nt * 256);
#pragma unroll
        for (int mt = 0; mt < 4; ++mt)
#pragma unroll
            for (int nt = 0; nt < 4; ++nt)
                acc[mt][nt] = __builtin_amdgcn_mfma_i32_16x16x64_i8(af[mt], bf[nt], acc[mt][nt], 0, 0, 0);
    };

    int sdb = 1;
#pragma unroll 1
    for (int p = 0; p < 4; ++p) {
        STAGE(sdb, 24576); ++sdb;
        COMPUTE(0);
        __syncthreads();
        if (p < 3) { STAGE(sdb, 0); ++sdb; }
        COMPUTE(24576);
        __syncthreads();
    }

    float scvv[4], scsv[4];
#pragma unroll
    for (int nt = 0; nt < 4; ++nt) {
        const int code = bn * 256 + wn * 64 + nt * 16 + l15;
        scvv[nt] = sc[code];
        scsv[nt] = scs[code];
    }
    float sxsv[4][4];
#pragma unroll
    for (int mt = 0; mt < 4; ++mt)
#pragma unroll
        for (int rr = 0; rr < 4; ++rr)
            sxsv[mt][rr] = sxs[bm * 128 + wm * 64 + mt * 16 + lk * 4 + rr];

#pragma unroll
    for (int mt = 0; mt < 4; ++mt)
#pragma unroll
        for (int nt = 0; nt < 4; ++nt)
#pragma unroll
            for (int rr = 0; rr < 4; ++rr) {
                const float df = (float)acc[mt][nt][rr];
                const float vv = fmaf(-2.0f * sxsv[mt][rr] * scsv[nt], df, scvv[nt]);
                acc[mt][nt][rr] = __float_as_int(vv);
            }
#define VACC(mt, nt, rr) __int_as_float(acc[mt][nt][rr])

#pragma unroll
    for (int mt = 0; mt < 4; ++mt)
#pragma unroll
        for (int rr = 0; rr < 4; ++rr) {
            float m4 = fminf(fminf(VACC(mt, 0, rr), VACC(mt, 1, rr)),
                             fminf(VACC(mt, 2, rr), VACC(mt, 3, rr)));
            m4 = fminf(m4, __shfl_xor(m4, 1, 64));
            m4 = fminf(m4, __shfl_xor(m4, 2, 64));
            m4 = fminf(m4, __shfl_xor(m4, 4, 64));
            m4 = fminf(m4, __shfl_xor(m4, 8, 64));
            if (l15 == 0) {
                const int tok = wm * 64 + mt * 16 + lk * 4 + rr;
                atomicMin(&minsh[tok], ordkey(m4));
            }
        }
    __syncthreads();

#pragma unroll
    for (int mt = 0; mt < 4; ++mt)
#pragma unroll
        for (int rr = 0; rr < 4; ++rr) {
            const int tok = wm * 64 + mt * 16 + lk * 4 + rr;
            const float tmn = fromkey(minsh[tok]) + MARGIN;
#pragma unroll
            for (int nt = 0; nt < 4; ++nt) {
                if (VACC(mt, nt, rr) <= tmn) {
                    unsigned p = atomicAdd(&cntsh[tok], 1u);
                    if (p < RCAP)
                        listsh[tok][p] = (unsigned short)(bn * 256 + wn * 64 + nt * 16 + l15);
                }
            }
        }
    __syncthreads();
#undef VACC

    if (t < 128) {
        const unsigned* lw = (const unsigned*)&listsh[t][0];
        uint4 r0, r1;
        r0.x = __float_as_uint(fromkey(minsh[t]));
        r0.y = cntsh[t];
        r0.z = lw[0]; r0.w = lw[1];
        r1.x = lw[2]; r1.y = lw[3]; r1.z = lw[4]; r1.w = lw[5];
        char* rp = records + ((size_t)(bm * 128 + t) * 16 + bn) * 32;
        *(uint4*)rp = r0;
        *(uint4*)(rp + 16) = r1;
    }
}

// ---------------- stage 2: fused resolve (compact + exec + gather, all in-LDS) --------
// Block = 64 tokens. Phase 1 (t<64): per-token threshold + LDS queue build (validated
// compact semantics). Phase 2: all 256 lanes drain the queue — one exact dot per
// candidate (bit-identical exact_dot512 / key semantics). Phase 3: gather rows.
// Overflow (>LCAP, probability ~0): in-block full exact scan of all 64 tokens.
__global__ __launch_bounds__(256)
void resolve_kernel(const float* __restrict__ inp, const float* __restrict__ cb,
                    const float* __restrict__ sc, const float* __restrict__ sxg,
                    const char* __restrict__ records, float* __restrict__ out) {
    __shared__ unsigned long long keysh[64];
    __shared__ unsigned qtot;
    __shared__ unsigned listq[LCAP];    // 12 KB: entry = tok(6b)<<12 | code(12b)
    __shared__ int bidx[64];

    const int t  = threadIdx.x;
    const int m0 = blockIdx.x * 64;

    if (t < 64) keysh[t] = 0xFFFFFFFFFFFFFFFFull;
    if (t == 0) qtot = 0u;
    __syncthreads();

    if (t < 64) {
        const char* rbase = records + (size_t)(m0 + t) * 16 * 32;
        float mn = __builtin_huge_valf();
#pragma unroll
        for (int i = 0; i < 16; ++i)
            mn = fminf(mn, *(const float*)(rbase + (size_t)i * 32));
        const float thr = mn + MARGIN;

        unsigned my = 0;
#pragma unroll 1
        for (int i = 0; i < 16; ++i) {
            const char* rp = rbase + (size_t)i * 32;
            if (*(const float*)rp <= thr) {
                const unsigned cnt = *(const unsigned*)(rp + 4);
                my += (cnt <= RCAP) ? cnt : 256u;
            }
        }
        unsigned pos = atomicAdd(&qtot, my);
#pragma unroll 1
        for (int i = 0; i < 16; ++i) {
            const char* rp = rbase + (size_t)i * 32;
            if (*(const float*)rp <= thr) {
                const unsigned cnt = *(const unsigned*)(rp + 4);
                if (cnt <= RCAP) {
                    const unsigned short* cs = (const unsigned short*)(rp + 8);
                    for (unsigned j = 0; j < cnt; ++j) {
                        if (pos < LCAP) listq[pos] = ((unsigned)t << 12) | cs[j];
                        ++pos;
                    }
                } else {
                    for (int c2 = 0; c2 < 256; ++c2) {
                        if (pos < LCAP) listq[pos] = ((unsigned)t << 12) | (unsigned)(i * 256 + c2);
                        ++pos;
                    }
                }
            }
        }
    }
    __syncthreads();

    const unsigned total = qtot;
    if (total <= (unsigned)LCAP) {
        for (unsigned i = t; i < total; i += 256) {
            const unsigned e = listq[i];
            const int tok  = e >> 12;
            const int code = e & 4095;
            const float dot = exact_dot512(inp + (size_t)(m0 + tok) * D, cb + (size_t)code * D);
            const float tmp = sxg[m0 + tok] - 2.0f * dot;   // -2*dot exact => contraction-immune
            const float v   = tmp + sc[code];
            const unsigned long long key =
                ((unsigned long long)__float_as_uint(v) << 32) | (unsigned)code;
            atomicMin(&keysh[tok], key);
        }
    } else {
        // overflow safety (never in practice): full exact scan, all 64 tokens
#pragma unroll 1
        for (int tok = 0; tok < 64; ++tok) {
            const float sxv = sxg[m0 + tok];
            const float* xrow = inp + (size_t)(m0 + tok) * D;
            for (int code = t; code < K; code += 256) {
                const float dot = exact_dot512(xrow, cb + (size_t)code * D);
                const float tmp = sxv - 2.0f * dot;
                const float v   = tmp + sc[code];
                const unsigned long long key =
                    ((unsigned long long)__float_as_uint(v) << 32) | (unsigned)code;
                atomicMin(&keysh[tok], key);
            }
        }
    }
    __syncthreads();

    if (t < 64) bidx[t] = (int)(keysh[t] & 0xFFFFFFFFull);
    __syncthreads();

    // gather: bit-exact codebook row copy (validated body)
    for (int q = t; q < 64 * (D / 4); q += 256) {
        const int r = q >> 7;
        const int c = (q & 127) * 4;
        *(float4*)(out + (size_t)(m0 + r) * D + c) = *(const float4*)(cb + (size_t)bidx[r] * D + c);
    }
}

// ================= LEGACY fallback path (round-1 validated) ==========
__global__ __launch_bounds__(256)
void sc_kernel(const float* __restrict__ cb, float* __restrict__ sc) {
    const int row  = blockIdx.x * 4 + (threadIdx.x >> 6);
    const int lane = threadIdx.x & 63;
    const float* r = cb + (size_t)row * D + lane * 8;
    float4 v0 = *(const float4*)r;
    float4 v1 = *(const float4*)(r + 4);
    float s = v0.x * v0.x;
    s += v0.y * v0.y; s += v0.z * v0.z; s += v0.w * v0.w;
    s += v1.x * v1.x; s += v1.y * v1.y; s += v1.z * v1.z; s += v1.w * v1.w;
#pragma unroll
    for (int off = 1; off < 64; off <<= 1) s += __shfl_xor(s, off, 64);
    if (lane == 0) sc[row] = s;
}

__global__ __launch_bounds__(256)
void vq_kernel(const float* __restrict__ inp, const float* __restrict__ cb,
               const float* __restrict__ sc, float* __restrict__ out) {
    __shared__ __align__(16) float As[BD_LEG][BM + PAD];
    __shared__ __align__(16) float Bs[BD_LEG][BN + PAD];
    __shared__ float sxl[BM];
    __shared__ float scs_l[BN];
    __shared__ int   bidx[BM];

    const int t  = threadIdx.x;
    const int m0 = blockIdx.x * BM;
    const int tm = t >> 4;
    const int tn = t & 15;
    const float FINF = __builtin_huge_valf();

    {
        const int r = t >> 2, p = t & 3;
        const float* row = inp + (size_t)(m0 + r) * D + p * 128;
        float s = 0.0f;
#pragma unroll
        for (int i = 0; i < 32; ++i) {
            float4 v = *(const float4*)(row + i * 4);
            s = fmaf(v.x, v.x, s); s = fmaf(v.y, v.y, s);
            s = fmaf(v.z, v.z, s); s = fmaf(v.w, v.w, s);
        }
        s += __shfl_xor(s, 1, 64);
        s += __shfl_xor(s, 2, 64);
        if (p == 0) sxl[r] = s;
    }
    __syncthreads();

    float sxm[4];
#pragma unroll
    for (int i = 0; i < 4; ++i) sxm[i] = sxl[tm * 4 + i];

    float runv[4] = {FINF, FINF, FINF, FINF};
    int   runi[4] = {0, 0, 0, 0};
    const int dq = (t & 7) << 2;
    const int mr = t >> 3;

#pragma unroll 1
    for (int kb = 0; kb < K; kb += BN) {
        __syncthreads();
        if (t < BN) scs_l[t] = sc[kb + t];

        float accl[4][4];
#pragma unroll
        for (int i = 0; i < 4; ++i)
#pragma unroll
            for (int j = 0; j < 4; ++j) accl[i][j] = 0.0f;

#pragma unroll 1
        for (int db = 0; db < D; db += BD_LEG) {
            const float* ap = inp + (size_t)(m0 + mr) * D + db + dq;
            const float* bp = cb  + (size_t)(kb + mr) * D + db + dq;
            float4 av0 = *(const float4*)ap;
            float4 av1 = *(const float4*)(ap + (size_t)32 * D);
            float4 bv0 = *(const float4*)bp;
            float4 bv1 = *(const float4*)(bp + (size_t)32 * D);
            __syncthreads();
            As[dq + 0][mr] = av0.x; As[dq + 1][mr] = av0.y;
            As[dq + 2][mr] = av0.z; As[dq + 3][mr] = av0.w;
            As[dq + 0][mr + 32] = av1.x; As[dq + 1][mr + 32] = av1.y;
            As[dq + 2][mr + 32] = av1.z; As[dq + 3][mr + 32] = av1.w;
            Bs[dq + 0][mr] = bv0.x; Bs[dq + 1][mr] = bv0.y;
            Bs[dq + 2][mr] = bv0.z; Bs[dq + 3][mr] = bv0.w;
            Bs[dq + 0][mr + 32] = bv1.x; Bs[dq + 1][mr + 32] = bv1.y;
            Bs[dq + 2][mr + 32] = bv1.z; Bs[dq + 3][mr + 32] = bv1.w;
            __syncthreads();
#pragma unroll
            for (int d = 0; d < BD_LEG; ++d) {
                const float4 a = *(const float4*)(&As[d][tm * 4]);
                const float4 b = *(const float4*)(&Bs[d][tn * 4]);
                float af[4] = {a.x, a.y, a.z, a.w};
                float bf[4] = {b.x, b.y, b.z, b.w};
#pragma unroll
                for (int i = 0; i < 4; ++i)
#pragma unroll
                    for (int j = 0; j < 4; ++j)
                        accl[i][j] = fmaf(af[i], bf[j], accl[i][j]);
            }
        }
#pragma unroll
        for (int i = 0; i < 4; ++i) {
            float bv = FINF;
            int   bi = 0x7fffffff;
#pragma unroll
            for (int j = 0; j < 4; ++j) {
                const float p = accl[i][j];
                const float tmp = sxm[i] - 2.0f * p;
                const float v   = tmp + scs_l[tn * 4 + j];
                const int  idx  = kb + tn * 4 + j;
                if (v < bv) { bv = v; bi = idx; }
            }
#pragma unroll
            for (int off = 1; off < 16; off <<= 1) {
                const float ov = __shfl_xor(bv, off, 64);
                const int   oi = __shfl_xor(bi, off, 64);
                if (ov < bv || (ov == bv && oi < bi)) { bv = ov; bi = oi; }
            }
            if (bv < runv[i]) { runv[i] = bv; runi[i] = bi; }
        }
    }
    if (tn == 0) {
#pragma unroll
        for (int i = 0; i < 4; ++i) bidx[tm * 4 + i] = runi[i];
    }
    __syncthreads();
#pragma unroll 1
    for (int q = t; q < BM * (D / 4); q += 256) {
        const int r = q >> 7;
        const int c = (q & 127) * 4;
        const float4 v = *(const float4*)(cb + (size_t)bidx[r] * D + c);
        *(float4*)(out + (size_t)(m0 + r) * D + c) = v;
    }
}

extern "C" void kernel_launch(void* const* d_in, const int* in_sizes, int n_in,
                              void* d_out, int out_size, void* d_ws, size_t ws_size,
                              hipStream_t stream) {
    const float* inp = (const float*)d_in[0];
    const float* cb  = (const float*)d_in[1];
    float* out = (float*)d_out;
    float* sc  = (float*)d_ws;
    const int tokens = in_sizes[0] / D;     // 32768

    const bool fast = (ws_size >= WS_NEED) && (tokens % 256 == 0) &&
                      (in_sizes[1] == K * D) &&
                      ((size_t)out_size * 4 >= (size_t)tokens * D + (size_t)tokens * 16 * 32);

    if (fast) {
        float* sxg = (float*)((char*)d_ws + SX_OFF);
        float* scsg = (float*)((char*)d_ws + SCS_OFF);
        float* sxsg = (float*)((char*)d_ws + SXS_OFF);
        unsigned char* cbp = (unsigned char*)((char*)d_ws + CBP_OFF);
        unsigned char* ap  = (unsigned char*)d_out;                         // 16 MB i8 scratch
        char* records = (char*)d_out + (size_t)tokens * D;                  // 16 MB scratch

        const int nb_cb = K / 64;   // 64 blocks of 64 rows

        prep_kernel<<<nb_cb + tokens / 64, 256, 0, stream>>>(cb, inp, sc, scsg, cbp,
                                                             sxg, sxsg, ap, nb_cb);
        score_kernel<<<(tokens / 128) * 16, 512, 0, stream>>>(ap, cbp, sc, scsg, sxsg, records);
        resolve_kernel<<<tokens / 64, 256, 0, stream>>>(inp, cb, sc, sxg, records, out);
    } else {
        sc_kernel<<<K / 4, 256, 0, stream>>>(cb, sc);
        vq_kernel<<<tokens / BM, 256, 0, stream>>>(inp, cb, sc, out);
    }
}